// Round 11
// baseline (308.677 us; speedup 1.0000x reference)
//
#include <hip/hip_runtime.h>
#include <cstddef>

constexpr int Bb  = 4;
constexpr int Nn  = 2048;
constexpr int Cc  = 256;
constexpr int Hh  = 128;
constexpr int NHh = 8;
constexpr int DHh = 16;
constexpr int MTOK = Bb * Nn;           // 8192 tokens
#define LOG2E 1.4426950408889634f

typedef __attribute__((ext_vector_type(8))) short bf16x8;
typedef __attribute__((ext_vector_type(4))) short bf16x4;
typedef __attribute__((ext_vector_type(4))) float f32x4;

__device__ __forceinline__ short f32_to_bf16_rne(float f) {
    union { float f; unsigned int u; } c; c.f = f;
    unsigned int r = c.u + 0x7fffu + ((c.u >> 16) & 1u);
    return (short)(r >> 16);
}
__device__ __forceinline__ float bf16_to_f32(short s) {
    union { float f; unsigned int u; } c; c.u = ((unsigned int)(unsigned short)s) << 16;
    return c.f;
}
__device__ __forceinline__ unsigned pack2_bf16(float a, float b) {
    unsigned ua = __float_as_uint(a);
    unsigned ub = __float_as_uint(b);
    ua += 0x7fffu + ((ua >> 16) & 1u);
    ub += 0x7fffu + ((ub >> 16) & 1u);
    return __builtin_amdgcn_perm(ub, ua, 0x07060302);
}

// ---------------------------------------------------------------------------
// fp32 -> bf16 conversion (weights + x) + zero the 4 quality accumulators
// ---------------------------------------------------------------------------
struct CvtJobs {
    const float* src[13];
    short*       dst[13];
    int          off[14];
    float*       qzero;
};

__global__ __launch_bounds__(256) void cvt_kernel(CvtJobs j) {
    const int gid = blockIdx.x * 256 + threadIdx.x;
    if (blockIdx.x == 0 && threadIdx.x < 4) j.qzero[threadIdx.x] = 0.f;
    if (gid >= j.off[13]) return;
    int k = 0;
    #pragma unroll
    for (int i = 0; i < 12; ++i) if (gid >= j.off[i + 1]) k = i + 1;
    const int idx = (gid - j.off[k]) * 4;
    float4 v = *(const float4*)(j.src[k] + idx);
    short o4[4] = { f32_to_bf16_rne(v.x), f32_to_bf16_rne(v.y),
                    f32_to_bf16_rne(v.z), f32_to_bf16_rne(v.w) };
    *(bf16x4*)(j.dst[k] + idx) = *(bf16x4*)o4;
}

// ---------------------------------------------------------------------------
// Plain bf16 MFMA GEMM (R3/R6-verified): 64x64 tile, BK=32, 4 waves.
// Used only for the qkv projection.
// ---------------------------------------------------------------------------
__global__ __launch_bounds__(256) void gemm_bf16_kernel(
    const short* __restrict__ X, const short* __restrict__ W,
    const float* __restrict__ bias, short* __restrict__ Yb,
    int M, int N, int K, int relu)
{
    __shared__ short As[64 * 40];
    __shared__ short Bs[64 * 40];

    const int tid  = threadIdx.x;
    const int lane = tid & 63;
    const int wv   = tid >> 6;
    const int col  = lane & 15;
    const int g    = lane >> 4;
    const int m0   = blockIdx.y * 64;
    const int n0   = blockIdx.x * 64;
    const int sr   = tid >> 2;
    const int sc   = (tid & 3) * 8;

    f32x4 acc[4] = {};

    for (int k0 = 0; k0 < K; k0 += 32) {
        __syncthreads();
        *(bf16x8*)&As[sr * 40 + sc] =
            *(const bf16x8*)(X + (size_t)(m0 + sr) * K + k0 + sc);
        *(bf16x8*)&Bs[sr * 40 + sc] =
            *(const bf16x8*)(W + (size_t)(n0 + sr) * K + k0 + sc);
        __syncthreads();

        bf16x8 a = *(bf16x8*)&As[(wv * 16 + col) * 40 + g * 8];
        #pragma unroll
        for (int jj = 0; jj < 4; ++jj) {
            bf16x8 b = *(bf16x8*)&Bs[(jj * 16 + col) * 40 + g * 8];
            acc[jj] = __builtin_amdgcn_mfma_f32_16x16x32_bf16(a, b, acc[jj], 0, 0, 0);
        }
    }

    #pragma unroll
    for (int jj = 0; jj < 4; ++jj) {
        const int cn = n0 + jj * 16 + col;
        const float bb = bias[cn];
        #pragma unroll
        for (int r = 0; r < 4; ++r) {
            const int rm = m0 + wv * 16 + g * 4 + r;
            float v = acc[jj][r] + bb;
            if (relu) v = fmaxf(v, 0.f);
            Yb[(size_t)rm * N + cn] = f32_to_bf16_rne(v);
        }
    }
}

// ---------------------------------------------------------------------------
// Fused GEMM(+bias) + residual + LayerNorm (R7-verified). Used for out-proj.
// ---------------------------------------------------------------------------
template<int K, int CR, bool DO_LN>
__global__ __launch_bounds__(256) void gemmln_kernel(
    const short* __restrict__ X, const short* __restrict__ W,
    const float* __restrict__ bias,
    float* __restrict__ hf, short* __restrict__ hb,
    const float* __restrict__ gw, const float* __restrict__ bw)
{
    constexpr int ST  = K + 8;
    constexpr int NCH = 128 / CR;
    constexpr int NF  = CR / 32;
    __shared__ short As[32 * ST];
    __shared__ short Ws[CR * ST];
    __shared__ float P[32 * 130];

    const int tid  = threadIdx.x;
    const int lane = tid & 63;
    const int wv   = tid >> 6;
    const int col  = lane & 15;
    const int g    = lane >> 4;
    const int m0   = blockIdx.x * 32;
    const int mst  = (wv & 1) * 16;
    const int cb   = (wv >> 1) * (CR / 2);

    for (int i = tid; i < 32 * (K / 8); i += 256) {
        const int r = i / (K / 8), c = (i % (K / 8)) * 8;
        *(bf16x8*)&As[r * ST + c] = *(const bf16x8*)(X + (size_t)(m0 + r) * K + c);
    }

    f32x4 ya[NCH][NF] = {};
    #pragma unroll
    for (int ch = 0; ch < NCH; ++ch) {
        for (int i = tid; i < CR * (K / 8); i += 256) {
            const int r = i / (K / 8), c = (i % (K / 8)) * 8;
            *(bf16x8*)&Ws[r * ST + c] =
                *(const bf16x8*)(W + (size_t)(ch * CR + r) * K + c);
        }
        __syncthreads();
        #pragma unroll
        for (int k0 = 0; k0 < K; k0 += 32) {
            bf16x8 a = *(bf16x8*)&As[(mst + col) * ST + k0 + g * 8];
            #pragma unroll
            for (int f = 0; f < NF; ++f) {
                bf16x8 b = *(bf16x8*)&Ws[(cb + f * 16 + col) * ST + k0 + g * 8];
                ya[ch][f] = __builtin_amdgcn_mfma_f32_16x16x32_bf16(a, b, ya[ch][f], 0, 0, 0);
            }
        }
        __syncthreads();
    }

    #pragma unroll
    for (int ch = 0; ch < NCH; ++ch)
        #pragma unroll
        for (int f = 0; f < NF; ++f) {
            const int cn = ch * CR + cb + f * 16 + col;
            const float bb = bias[cn];
            #pragma unroll
            for (int r = 0; r < 4; ++r)
                P[(mst + g * 4 + r) * 130 + cn] = ya[ch][f][r] + bb;
        }
    __syncthreads();

    #pragma unroll
    for (int rr = 0; rr < 8; ++rr) {
        const int row = wv * 8 + rr;
        const size_t t = m0 + row;
        float2 pv = *(float2*)&P[row * 130 + 2 * lane];
        if (DO_LN) {
            float2 hv = ((const float2*)(hf + t * Hh))[lane];
            float a0 = hv.x + pv.x, a1 = hv.y + pv.y;
            float sum = a0 + a1;
            #pragma unroll
            for (int off = 32; off > 0; off >>= 1) sum += __shfl_xor(sum, off);
            const float mean = sum * (1.f / 128.f);
            const float d0 = a0 - mean, d1 = a1 - mean;
            float vs = d0 * d0 + d1 * d1;
            #pragma unroll
            for (int off = 32; off > 0; off >>= 1) vs += __shfl_xor(vs, off);
            const float rstd = rsqrtf(vs * (1.f / 128.f) + 1e-5f);
            float2 gv = ((const float2*)gw)[lane];
            float2 bv = ((const float2*)bw)[lane];
            float2 r = { d0 * rstd * gv.x + bv.x, d1 * rstd * gv.y + bv.y };
            ((float2*)(hf + t * Hh))[lane] = r;
            *(unsigned*)&hb[t * Hh + lane * 2] = pack2_bf16(r.x, r.y);
        } else {
            ((float2*)(hf + t * Hh))[lane] = pv;
            *(unsigned*)&hb[t * Hh + lane * 2] = pack2_bf16(pv.x, pv.y);
        }
    }
}

// ---------------------------------------------------------------------------
// Two-stage fused MLP (R9-verified)
// ---------------------------------------------------------------------------
template<int K, int MID, int CR1, int CR2, bool DO_LN>
__global__ __launch_bounds__(256) void mlp2_kernel(
    const short* __restrict__ X,
    const short* __restrict__ W1, const float* __restrict__ b1,
    const short* __restrict__ W2, const float* __restrict__ b2,
    float* __restrict__ hf, short* __restrict__ hb,
    const float* __restrict__ gw, const float* __restrict__ bw)
{
    constexpr int STA = K + 8;
    constexpr int STU = MID + 8;
    constexpr int WS1 = CR1 * STA;
    constexpr int WS2 = CR2 * STU;
    constexpr int WSZ = (WS1 > WS2) ? WS1 : WS2;
    __shared__ short As[32 * STA];
    __shared__ short Ws[WSZ];
    __shared__ short U[32 * STU];
    __shared__ float P[32 * 130];

    const int tid  = threadIdx.x;
    const int lane = tid & 63;
    const int wv   = tid >> 6;
    const int col  = lane & 15;
    const int g    = lane >> 4;
    const int m0   = blockIdx.x * 32;
    const int mst  = (wv & 1) * 16;

    for (int i = tid; i < 32 * (K / 8); i += 256) {
        const int r = i / (K / 8), c = (i % (K / 8)) * 8;
        *(bf16x8*)&As[r * STA + c] = *(const bf16x8*)(X + (size_t)(m0 + r) * K + c);
    }

    constexpr int NCH1 = MID / CR1;
    constexpr int NF1  = CR1 / 32;
    const int cb1 = (wv >> 1) * (CR1 / 2);
    #pragma unroll
    for (int ch = 0; ch < NCH1; ++ch) {
        for (int i = tid; i < CR1 * (K / 8); i += 256) {
            const int r = i / (K / 8), c = (i % (K / 8)) * 8;
            *(bf16x8*)&Ws[r * STA + c] =
                *(const bf16x8*)(W1 + (size_t)(ch * CR1 + r) * K + c);
        }
        __syncthreads();
        f32x4 ya[NF1] = {};
        #pragma unroll
        for (int k0 = 0; k0 < K; k0 += 32) {
            bf16x8 a = *(bf16x8*)&As[(mst + col) * STA + k0 + g * 8];
            #pragma unroll
            for (int f = 0; f < NF1; ++f) {
                bf16x8 b = *(bf16x8*)&Ws[(cb1 + f * 16 + col) * STA + k0 + g * 8];
                ya[f] = __builtin_amdgcn_mfma_f32_16x16x32_bf16(a, b, ya[f], 0, 0, 0);
            }
        }
        #pragma unroll
        for (int f = 0; f < NF1; ++f) {
            const int cn = ch * CR1 + cb1 + f * 16 + col;
            const float bb = b1[cn];
            #pragma unroll
            for (int r = 0; r < 4; ++r)
                U[(mst + g * 4 + r) * STU + cn] =
                    f32_to_bf16_rne(fmaxf(ya[f][r] + bb, 0.f));
        }
        __syncthreads();
    }

    constexpr int NCH2 = 128 / CR2;
    constexpr int NF2  = CR2 / 32;
    const int cb2 = (wv >> 1) * (CR2 / 2);
    f32x4 yb[NCH2][NF2] = {};
    #pragma unroll
    for (int ch = 0; ch < NCH2; ++ch) {
        for (int i = tid; i < CR2 * (MID / 8); i += 256) {
            const int r = i / (MID / 8), c = (i % (MID / 8)) * 8;
            *(bf16x8*)&Ws[r * STU + c] =
                *(const bf16x8*)(W2 + (size_t)(ch * CR2 + r) * MID + c);
        }
        __syncthreads();
        #pragma unroll
        for (int k0 = 0; k0 < MID; k0 += 32) {
            bf16x8 a = *(bf16x8*)&U[(mst + col) * STU + k0 + g * 8];
            #pragma unroll
            for (int f = 0; f < NF2; ++f) {
                bf16x8 b = *(bf16x8*)&Ws[(cb2 + f * 16 + col) * STU + k0 + g * 8];
                yb[ch][f] = __builtin_amdgcn_mfma_f32_16x16x32_bf16(a, b, yb[ch][f], 0, 0, 0);
            }
        }
        __syncthreads();
    }

    #pragma unroll
    for (int ch = 0; ch < NCH2; ++ch)
        #pragma unroll
        for (int f = 0; f < NF2; ++f) {
            const int cn = ch * CR2 + cb2 + f * 16 + col;
            const float bb = b2[cn];
            #pragma unroll
            for (int r = 0; r < 4; ++r)
                P[(mst + g * 4 + r) * 130 + cn] = yb[ch][f][r] + bb;
        }
    __syncthreads();

    #pragma unroll
    for (int rr = 0; rr < 8; ++rr) {
        const int row = wv * 8 + rr;
        const size_t t = m0 + row;
        float2 pv = *(float2*)&P[row * 130 + 2 * lane];
        if (DO_LN) {
            float2 hv = ((const float2*)(hf + t * Hh))[lane];
            float a0 = hv.x + pv.x, a1 = hv.y + pv.y;
            float sum = a0 + a1;
            #pragma unroll
            for (int off = 32; off > 0; off >>= 1) sum += __shfl_xor(sum, off);
            const float mean = sum * (1.f / 128.f);
            const float d0 = a0 - mean, d1 = a1 - mean;
            float vs = d0 * d0 + d1 * d1;
            #pragma unroll
            for (int off = 32; off > 0; off >>= 1) vs += __shfl_xor(vs, off);
            const float rstd = rsqrtf(vs * (1.f / 128.f) + 1e-5f);
            float2 gv = ((const float2*)gw)[lane];
            float2 bv = ((const float2*)bw)[lane];
            float2 r = { d0 * rstd * gv.x + bv.x, d1 * rstd * gv.y + bv.y };
            ((float2*)(hf + t * Hh))[lane] = r;
            *(unsigned*)&hb[t * Hh + lane * 2] = pack2_bf16(r.x, r.y);
        } else {
            ((float2*)(hf + t * Hh))[lane] = pv;
            *(unsigned*)&hb[t * Hh + lane * 2] = pack2_bf16(pv.x, pv.y);
        }
    }
}

// ---------------------------------------------------------------------------
// Fused head (R7-verified)
// ---------------------------------------------------------------------------
__global__ __launch_bounds__(256) void head_kernel(
    const short* __restrict__ X,
    const short* __restrict__ W1b, const float* __restrict__ b1,
    const short* __restrict__ DW1b, const float* __restrict__ db1,
    const float* __restrict__ w2, const float* __restrict__ b2,
    const float* __restrict__ dw2, const float* __restrict__ db2,
    float* __restrict__ out)
{
    constexpr int K = 128, ST = K + 8;
    __shared__ short As[32 * ST];
    __shared__ short Ws[64 * ST];
    __shared__ float P[32 * 196];

    const int tid  = threadIdx.x;
    const int lane = tid & 63;
    const int wv   = tid >> 6;
    const int col  = lane & 15;
    const int g    = lane >> 4;
    const int m0   = blockIdx.x * 32;
    const int mst  = (wv & 1) * 16;
    const int cb   = (wv >> 1) * 32;

    for (int i = tid; i < 32 * (K / 8); i += 256) {
        const int r = i / (K / 8), c = (i % (K / 8)) * 8;
        *(bf16x8*)&As[r * ST + c] = *(const bf16x8*)(X + (size_t)(m0 + r) * K + c);
    }

    f32x4 ya[3][2] = {};
    #pragma unroll
    for (int ch = 0; ch < 3; ++ch) {
        for (int i = tid; i < 64 * (K / 8); i += 256) {
            const int r = i / (K / 8), c = (i % (K / 8)) * 8;
            const int rg = ch * 64 + r;
            const short* src = (rg < 128) ? (W1b + (size_t)rg * K)
                                          : (DW1b + (size_t)(rg - 128) * K);
            *(bf16x8*)&Ws[r * ST + c] = *(const bf16x8*)(src + c);
        }
        __syncthreads();
        #pragma unroll
        for (int k0 = 0; k0 < K; k0 += 32) {
            bf16x8 a = *(bf16x8*)&As[(mst + col) * ST + k0 + g * 8];
            #pragma unroll
            for (int f = 0; f < 2; ++f) {
                bf16x8 b = *(bf16x8*)&Ws[(cb + f * 16 + col) * ST + k0 + g * 8];
                ya[ch][f] = __builtin_amdgcn_mfma_f32_16x16x32_bf16(a, b, ya[ch][f], 0, 0, 0);
            }
        }
        __syncthreads();
    }

    #pragma unroll
    for (int ch = 0; ch < 3; ++ch)
        #pragma unroll
        for (int f = 0; f < 2; ++f) {
            const int cn = ch * 64 + cb + f * 16 + col;
            const float bb = (cn < 128) ? b1[cn] : db1[cn - 128];
            #pragma unroll
            for (int r = 0; r < 4; ++r)
                P[(mst + g * 4 + r) * 196 + cn] = fmaxf(ya[ch][f][r] + bb, 0.f);
        }
    __syncthreads();

    const float w20 = w2[2 * lane],       w21 = w2[2 * lane + 1];
    const float w22 = w2[128 + 2 * lane], w23 = w2[129 + 2 * lane];
    const float w24 = w2[256 + 2 * lane], w25 = w2[257 + 2 * lane];
    const float dwl = dw2[lane];
    float qacc = 0.f;
    #pragma unroll
    for (int rr = 0; rr < 8; ++rr) {
        const int row = wv * 8 + rr;
        const size_t t = m0 + row;
        const float x0 = P[row * 196 + 2 * lane];
        const float x1 = P[row * 196 + 2 * lane + 1];
        float s0 = x0 * w20 + x1 * w21;
        float s1 = x0 * w22 + x1 * w23;
        float s2 = x0 * w24 + x1 * w25;
        float d  = P[row * 196 + 128 + lane] * dwl;
        #pragma unroll
        for (int off = 32; off > 0; off >>= 1) {
            s0 += __shfl_xor(s0, off);
            s1 += __shfl_xor(s1, off);
            s2 += __shfl_xor(s2, off);
            d  += __shfl_xor(d,  off);
        }
        if (lane == 0) {
            out[t * 3 + 0] = s0 + b2[0];
            out[t * 3 + 1] = s1 + b2[1];
            out[t * 3 + 2] = s2 + b2[2];
            const float prob = 1.f / (1.f + __expf(-(d + db2[0])));
            out[24576 + t] = prob;
            qacc += prob;
        }
    }
    if (lane == 0)
        atomicAdd(&out[32768 + (m0 >> 11)], qacc * (1.f / (float)Nn));
}

// ---------------------------------------------------------------------------
// MFMA flash attention, split-K 4-way. R9's verified kernel with the key loop
// restricted to this block's 512-key range; partial (o, l) written to ws.
// No-max softmax makes the combine an exact sum.
// ---------------------------------------------------------------------------
constexpr int KT = 128;
constexpr int KS = 28;
constexpr int VS = 132;
constexpr int NSPLIT = 4;
constexpr int KCH = Nn / NSPLIT;   // 512 keys per block

__global__ __launch_bounds__(256) void attn_kernel(
    const short* __restrict__ qkv, float* __restrict__ o_ws,
    float* __restrict__ l_ws)
{
    __shared__ short Ks[KT * KS];
    __shared__ short Vs[DHh * VS];

    const int tid  = threadIdx.x;
    const int lane = tid & 63;
    const int wv   = tid >> 6;
    const int col  = lane & 15;
    const int g    = lane >> 4;
    const int hd   = blockIdx.y;
    const int b    = blockIdx.z;
    const int sp   = blockIdx.x & (NSPLIT - 1);
    const int qb   = blockIdx.x >> 2;
    const int q0   = qb * 64 + wv * 16;

    const short* base = qkv + (size_t)b * Nn * 384;

    bf16x8 qf = {};
    if (g < 2) {
        bf16x8 qraw = *(const bf16x8*)(base + (size_t)(q0 + col) * 384 + hd * DHh + g * 8);
        const float qs = 0.25f * LOG2E;
        #pragma unroll
        for (int i = 0; i < 8; ++i)
            qf[i] = f32_to_bf16_rne(bf16_to_f32(qraw[i]) * qs);
    }

    f32x4 o    = {0.f, 0.f, 0.f, 0.f};
    f32x4 lacc = {0.f, 0.f, 0.f, 0.f};
    const short one_bf16 = (short)0x3F80;
    const bf16x8 ones = { one_bf16, one_bf16, one_bf16, one_bf16,
                          one_bf16, one_bf16, one_bf16, one_bf16 };

    const int ksr = tid >> 1;
    const int ksd = (tid & 1) * 8;
    const int va  = tid >> 2;
    const int vd  = (tid & 3) * 4;

    for (int kt = sp * KCH; kt < (sp + 1) * KCH; kt += KT) {
        __syncthreads();
        {
            *(bf16x8*)&Ks[ksr * KS + ksd] =
                *(const bf16x8*)(base + (size_t)(kt + ksr) * 384 + Hh + hd * DHh + ksd);
            const short* v0 = base + (size_t)(kt + 2 * va) * 384 + 2 * Hh + hd * DHh + vd;
            bf16x4 r0 = *(const bf16x4*)v0;
            bf16x4 r1 = *(const bf16x4*)(v0 + 384);
            unsigned a0 = ((const unsigned*)&r0)[0], a1 = ((const unsigned*)&r0)[1];
            unsigned b0 = ((const unsigned*)&r1)[0], b1 = ((const unsigned*)&r1)[1];
            *(unsigned*)&Vs[(vd + 0) * VS + 2 * va] = __builtin_amdgcn_perm(b0, a0, 0x05040100);
            *(unsigned*)&Vs[(vd + 1) * VS + 2 * va] = __builtin_amdgcn_perm(b0, a0, 0x07060302);
            *(unsigned*)&Vs[(vd + 2) * VS + 2 * va] = __builtin_amdgcn_perm(b1, a1, 0x05040100);
            *(unsigned*)&Vs[(vd + 3) * VS + 2 * va] = __builtin_amdgcn_perm(b1, a1, 0x07060302);
        }
        __syncthreads();

        #pragma unroll
        for (int s = 0; s < 4; ++s) {
            bf16x8 kf0 = {}, kf1 = {};
            if (g < 2) {
                kf0 = *(bf16x8*)&Ks[(s * 32 + col) * KS + g * 8];
                kf1 = *(bf16x8*)&Ks[(s * 32 + 16 + col) * KS + g * 8];
            }
            f32x4 z = {0.f, 0.f, 0.f, 0.f};
            f32x4 sA = __builtin_amdgcn_mfma_f32_16x16x32_bf16(kf0, qf, z, 0, 0, 0);
            f32x4 sB = __builtin_amdgcn_mfma_f32_16x16x32_bf16(kf1, qf, z, 0, 0, 0);

            union { bf16x8 v; unsigned u[4]; } pf;
            pf.u[0] = pack2_bf16(__builtin_amdgcn_exp2f(sA[0]),
                                 __builtin_amdgcn_exp2f(sA[1]));
            pf.u[1] = pack2_bf16(__builtin_amdgcn_exp2f(sA[2]),
                                 __builtin_amdgcn_exp2f(sA[3]));
            pf.u[2] = pack2_bf16(__builtin_amdgcn_exp2f(sB[0]),
                                 __builtin_amdgcn_exp2f(sB[1]));
            pf.u[3] = pack2_bf16(__builtin_amdgcn_exp2f(sB[2]),
                                 __builtin_amdgcn_exp2f(sB[3]));

            bf16x8 vf;
            ((bf16x4*)&vf)[0] = *(bf16x4*)&Vs[col * VS + s * 32 + g * 4];
            ((bf16x4*)&vf)[1] = *(bf16x4*)&Vs[col * VS + s * 32 + 16 + g * 4];

            o    = __builtin_amdgcn_mfma_f32_16x16x32_bf16(pf.v, vf,   o,    0, 0, 0);
            lacc = __builtin_amdgcn_mfma_f32_16x16x32_bf16(pf.v, ones, lacc, 0, 0, 0);
        }
    }

    // write partials: o (fp32) and l (one writer per query: col==0 lanes)
    #pragma unroll
    for (int r = 0; r < 4; ++r) {
        const size_t t = (size_t)b * Nn + q0 + g * 4 + r;
        o_ws[((size_t)sp * MTOK + t) * Hh + hd * DHh + col] = o[r];
        if (col == 0)
            l_ws[((size_t)sp * MTOK + t) * NHh + hd] = lacc[r];
    }
}

// combine split-K partials: attno[t][d] = (sum_sp o) / (sum_sp l)
__global__ __launch_bounds__(256) void attn_reduce_kernel(
    const float* __restrict__ o_ws, const float* __restrict__ l_ws,
    short* __restrict__ attno)
{
    const int gid = blockIdx.x * 256 + threadIdx.x;   // MTOK*64
    const int t   = gid >> 6;
    const int dp  = (gid & 63) * 2;
    const int hd  = dp >> 4;
    float ox = 0.f, oy = 0.f, ls = 0.f;
    #pragma unroll
    for (int sp = 0; sp < NSPLIT; ++sp) {
        float2 ov = *(const float2*)&o_ws[((size_t)sp * MTOK + t) * Hh + dp];
        ox += ov.x; oy += ov.y;
        ls += l_ws[((size_t)sp * MTOK + t) * NHh + hd];
    }
    const float inv = __builtin_amdgcn_rcpf(ls);
    *(unsigned*)&attno[(size_t)t * Hh + dp] = pack2_bf16(ox * inv, oy * inv);
}

// ---------------------------------------------------------------------------
extern "C" void kernel_launch(void* const* d_in, const int* in_sizes, int n_in,
                              void* d_out, int out_size, void* d_ws, size_t ws_size,
                              hipStream_t stream)
{
    char* W8 = (char*)d_ws;
    float* hf   = (float*)(W8 + 0);            // 4MB  fp32 residual spine
    short* hb   = (short*)(W8 + 4194304);      // 2MB  bf16 mirror
    short* wb   = (short*)(W8 + 6291456);      // 1MB  bf16 weights
    char*  regA = W8 + 7340032;                // 6MB  xb / qkvb
    char*  regB = W8 + 13631488;               // 2MB  attno
    float* o_ws = (float*)(W8 + 16777216);     // 16MB split-K o partials
    float* l_ws = (float*)(W8 + 33554432);     // 1MB  split-K l partials

    short* xb    = (short*)regA;               // [8192,256]
    short* qkvb  = (short*)regA;               // [8192,384]
    short* attno = (short*)regB;               // [8192,128]
    float* out   = (float*)d_out;

    const int wsz[12]  = {32768,16384,49152,16384,32768,32768,49152,16384,32768,32768,16384,8192};
    const int wsrc[12] = {1, 3, 5, 7, 9, 11, 17, 19, 21, 23, 29, 33};
    int woff[13]; woff[0] = 0;
    for (int i = 0; i < 12; ++i) woff[i + 1] = woff[i] + wsz[i];

    CvtJobs jobs;
    int acc = 0;
    for (int i = 0; i < 12; ++i) {
        jobs.src[i] = (const float*)d_in[wsrc[i]];
        jobs.dst[i] = wb + woff[i];
        jobs.off[i] = acc;
        acc += wsz[i] / 4;
    }
    jobs.src[12] = (const float*)d_in[0];
    jobs.dst[12] = xb;
    jobs.off[12] = acc;
    acc += (MTOK * Cc) / 4;
    jobs.off[13] = acc;
    jobs.qzero = out + 32768;

    hipLaunchKernelGGL(cvt_kernel, dim3((acc + 255) / 256), dim3(256), 0, stream, jobs);

    // feature fusion: h = relu(x@fw1^T+b1)@fw2^T+b2  (one fused dispatch)
    hipLaunchKernelGGL((mlp2_kernel<256, 128, 32, 64, false>), dim3(MTOK / 32), dim3(256), 0,
                       stream, xb, wb + woff[0], (const float*)d_in[2],
                       wb + woff[1], (const float*)d_in[4], hf, hb, nullptr, nullptr);

    for (int l = 0; l < 2; ++l) {
        const int ib = 5 + l * 12;
        const int wbase = 2 + l * 4;
        hipLaunchKernelGGL(gemm_bf16_kernel, dim3(384 / 64, MTOK / 64), dim3(256), 0, stream,
                           hb, wb + woff[wbase + 0], (const float*)d_in[ib + 1], qkvb,
                           MTOK, 3 * Hh, Hh, 0);
        hipLaunchKernelGGL(attn_kernel, dim3((Nn / 64) * NSPLIT, NHh, Bb), dim3(256), 0,
                           stream, qkvb, o_ws, l_ws);
        hipLaunchKernelGGL(attn_reduce_kernel, dim3(MTOK * 64 / 256), dim3(256), 0, stream,
                           o_ws, l_ws, attno);
        hipLaunchKernelGGL((gemmln_kernel<128, 64, true>), dim3(MTOK / 32), dim3(256), 0, stream,
                           attno, wb + woff[wbase + 1], (const float*)d_in[ib + 3],
                           hf, hb, (const float*)d_in[ib + 8], (const float*)d_in[ib + 9]);
        // fused FFN: h = LN(h + relu(h@f1^T+b1)@f2^T+b2)
        hipLaunchKernelGGL((mlp2_kernel<128, 256, 64, 32, true>), dim3(MTOK / 32), dim3(256), 0,
                           stream, hb, wb + woff[wbase + 2], (const float*)d_in[ib + 5],
                           wb + woff[wbase + 3], (const float*)d_in[ib + 7],
                           hf, hb, (const float*)d_in[ib + 10], (const float*)d_in[ib + 11]);
    }

    hipLaunchKernelGGL(head_kernel, dim3(MTOK / 32), dim3(256), 0, stream,
                       hb, wb + woff[10], (const float*)d_in[30],
                       wb + woff[11], (const float*)d_in[34],
                       (const float*)d_in[31], (const float*)d_in[32],
                       (const float*)d_in[35], (const float*)d_in[36], out);
}

// Round 12
// 299.868 us; speedup vs baseline: 1.0294x; 1.0294x over previous
//
#include <hip/hip_runtime.h>
#include <cstddef>

constexpr int Bb  = 4;
constexpr int Nn  = 2048;
constexpr int Cc  = 256;
constexpr int Hh  = 128;
constexpr int NHh = 8;
constexpr int DHh = 16;
constexpr int MTOK = Bb * Nn;           // 8192 tokens
#define LOG2E 1.4426950408889634f

typedef __attribute__((ext_vector_type(8))) short bf16x8;
typedef __attribute__((ext_vector_type(4))) short bf16x4;
typedef __attribute__((ext_vector_type(4))) float f32x4;

__device__ __forceinline__ short f32_to_bf16_rne(float f) {
    union { float f; unsigned int u; } c; c.f = f;
    unsigned int r = c.u + 0x7fffu + ((c.u >> 16) & 1u);
    return (short)(r >> 16);
}
__device__ __forceinline__ float bf16_to_f32(short s) {
    union { float f; unsigned int u; } c; c.u = ((unsigned int)(unsigned short)s) << 16;
    return c.f;
}
__device__ __forceinline__ unsigned pack2_bf16(float a, float b) {
    unsigned ua = __float_as_uint(a);
    unsigned ub = __float_as_uint(b);
    ua += 0x7fffu + ((ua >> 16) & 1u);
    ub += 0x7fffu + ((ub >> 16) & 1u);
    return __builtin_amdgcn_perm(ub, ua, 0x07060302);
}

// ---------------------------------------------------------------------------
// fp32 -> bf16 conversion (weights + x) + zero the 4 quality accumulators
// ---------------------------------------------------------------------------
struct CvtJobs {
    const float* src[13];
    short*       dst[13];
    int          off[14];
    float*       qzero;
};

__global__ __launch_bounds__(256) void cvt_kernel(CvtJobs j) {
    const int gid = blockIdx.x * 256 + threadIdx.x;
    if (blockIdx.x == 0 && threadIdx.x < 4) j.qzero[threadIdx.x] = 0.f;
    if (gid >= j.off[13]) return;
    int k = 0;
    #pragma unroll
    for (int i = 0; i < 12; ++i) if (gid >= j.off[i + 1]) k = i + 1;
    const int idx = (gid - j.off[k]) * 4;
    float4 v = *(const float4*)(j.src[k] + idx);
    short o4[4] = { f32_to_bf16_rne(v.x), f32_to_bf16_rne(v.y),
                    f32_to_bf16_rne(v.z), f32_to_bf16_rne(v.w) };
    *(bf16x4*)(j.dst[k] + idx) = *(bf16x4*)o4;
}

// ---------------------------------------------------------------------------
// qkv GEMM: 64x64 tile (R3/R6-verified datapath), epilogue writes HEAD-MAJOR
// layout: Q/K/V as three [b*NH][N][16] tensors (section = MTOK*128 elems).
// Coalescing of the write is unchanged (16 lanes -> 32B contiguous).
// ---------------------------------------------------------------------------
__global__ __launch_bounds__(256) void gemm_qkv_kernel(
    const short* __restrict__ X, const short* __restrict__ W,
    const float* __restrict__ bias, short* __restrict__ Yb)
{
    constexpr int K = 128, N = 384;
    __shared__ short As[64 * 40];
    __shared__ short Bs[64 * 40];

    const int tid  = threadIdx.x;
    const int lane = tid & 63;
    const int wv   = tid >> 6;
    const int col  = lane & 15;
    const int g    = lane >> 4;
    const int m0   = blockIdx.y * 64;
    const int n0   = blockIdx.x * 64;
    const int sr   = tid >> 2;
    const int sc   = (tid & 3) * 8;

    f32x4 acc[4] = {};

    for (int k0 = 0; k0 < K; k0 += 32) {
        __syncthreads();
        *(bf16x8*)&As[sr * 40 + sc] =
            *(const bf16x8*)(X + (size_t)(m0 + sr) * K + k0 + sc);
        *(bf16x8*)&Bs[sr * 40 + sc] =
            *(const bf16x8*)(W + (size_t)(n0 + sr) * K + k0 + sc);
        __syncthreads();

        bf16x8 a = *(bf16x8*)&As[(wv * 16 + col) * 40 + g * 8];
        #pragma unroll
        for (int jj = 0; jj < 4; ++jj) {
            bf16x8 b = *(bf16x8*)&Bs[(jj * 16 + col) * 40 + g * 8];
            acc[jj] = __builtin_amdgcn_mfma_f32_16x16x32_bf16(a, b, acc[jj], 0, 0, 0);
        }
    }

    #pragma unroll
    for (int jj = 0; jj < 4; ++jj) {
        const int cn  = n0 + jj * 16 + col;
        const int sec = cn >> 7;            // 0=q 1=k 2=v
        const int hd  = (cn & 127) >> 4;
        const int d   = cn & 15;
        const float bb = bias[cn];
        #pragma unroll
        for (int r = 0; r < 4; ++r) {
            const int rm = m0 + wv * 16 + g * 4 + r;   // token = b*2048+tt
            const int bq = rm >> 11, tt = rm & 2047;
            float v = acc[jj][r] + bb;
            Yb[(size_t)sec * (MTOK * 128)
               + ((size_t)(bq * NHh + hd) * Nn + tt) * DHh + d] = f32_to_bf16_rne(v);
        }
    }
}

// ---------------------------------------------------------------------------
// Fused GEMM(+bias) + residual + LayerNorm (R7-verified). Used for out-proj.
// ---------------------------------------------------------------------------
template<int K, int CR, bool DO_LN>
__global__ __launch_bounds__(256) void gemmln_kernel(
    const short* __restrict__ X, const short* __restrict__ W,
    const float* __restrict__ bias,
    float* __restrict__ hf, short* __restrict__ hb,
    const float* __restrict__ gw, const float* __restrict__ bw)
{
    constexpr int ST  = K + 8;
    constexpr int NCH = 128 / CR;
    constexpr int NF  = CR / 32;
    __shared__ short As[32 * ST];
    __shared__ short Ws[CR * ST];
    __shared__ float P[32 * 130];

    const int tid  = threadIdx.x;
    const int lane = tid & 63;
    const int wv   = tid >> 6;
    const int col  = lane & 15;
    const int g    = lane >> 4;
    const int m0   = blockIdx.x * 32;
    const int mst  = (wv & 1) * 16;
    const int cb   = (wv >> 1) * (CR / 2);

    for (int i = tid; i < 32 * (K / 8); i += 256) {
        const int r = i / (K / 8), c = (i % (K / 8)) * 8;
        *(bf16x8*)&As[r * ST + c] = *(const bf16x8*)(X + (size_t)(m0 + r) * K + c);
    }

    f32x4 ya[NCH][NF] = {};
    #pragma unroll
    for (int ch = 0; ch < NCH; ++ch) {
        for (int i = tid; i < CR * (K / 8); i += 256) {
            const int r = i / (K / 8), c = (i % (K / 8)) * 8;
            *(bf16x8*)&Ws[r * ST + c] =
                *(const bf16x8*)(W + (size_t)(ch * CR + r) * K + c);
        }
        __syncthreads();
        #pragma unroll
        for (int k0 = 0; k0 < K; k0 += 32) {
            bf16x8 a = *(bf16x8*)&As[(mst + col) * ST + k0 + g * 8];
            #pragma unroll
            for (int f = 0; f < NF; ++f) {
                bf16x8 b = *(bf16x8*)&Ws[(cb + f * 16 + col) * ST + k0 + g * 8];
                ya[ch][f] = __builtin_amdgcn_mfma_f32_16x16x32_bf16(a, b, ya[ch][f], 0, 0, 0);
            }
        }
        __syncthreads();
    }

    #pragma unroll
    for (int ch = 0; ch < NCH; ++ch)
        #pragma unroll
        for (int f = 0; f < NF; ++f) {
            const int cn = ch * CR + cb + f * 16 + col;
            const float bb = bias[cn];
            #pragma unroll
            for (int r = 0; r < 4; ++r)
                P[(mst + g * 4 + r) * 130 + cn] = ya[ch][f][r] + bb;
        }
    __syncthreads();

    #pragma unroll
    for (int rr = 0; rr < 8; ++rr) {
        const int row = wv * 8 + rr;
        const size_t t = m0 + row;
        float2 pv = *(float2*)&P[row * 130 + 2 * lane];
        if (DO_LN) {
            float2 hv = ((const float2*)(hf + t * Hh))[lane];
            float a0 = hv.x + pv.x, a1 = hv.y + pv.y;
            float sum = a0 + a1;
            #pragma unroll
            for (int off = 32; off > 0; off >>= 1) sum += __shfl_xor(sum, off);
            const float mean = sum * (1.f / 128.f);
            const float d0 = a0 - mean, d1 = a1 - mean;
            float vs = d0 * d0 + d1 * d1;
            #pragma unroll
            for (int off = 32; off > 0; off >>= 1) vs += __shfl_xor(vs, off);
            const float rstd = rsqrtf(vs * (1.f / 128.f) + 1e-5f);
            float2 gv = ((const float2*)gw)[lane];
            float2 bv = ((const float2*)bw)[lane];
            float2 r = { d0 * rstd * gv.x + bv.x, d1 * rstd * gv.y + bv.y };
            ((float2*)(hf + t * Hh))[lane] = r;
            *(unsigned*)&hb[t * Hh + lane * 2] = pack2_bf16(r.x, r.y);
        } else {
            ((float2*)(hf + t * Hh))[lane] = pv;
            *(unsigned*)&hb[t * Hh + lane * 2] = pack2_bf16(pv.x, pv.y);
        }
    }
}

// ---------------------------------------------------------------------------
// Two-stage fused MLP (R9-verified)
// ---------------------------------------------------------------------------
template<int K, int MID, int CR1, int CR2, bool DO_LN>
__global__ __launch_bounds__(256) void mlp2_kernel(
    const short* __restrict__ X,
    const short* __restrict__ W1, const float* __restrict__ b1,
    const short* __restrict__ W2, const float* __restrict__ b2,
    float* __restrict__ hf, short* __restrict__ hb,
    const float* __restrict__ gw, const float* __restrict__ bw)
{
    constexpr int STA = K + 8;
    constexpr int STU = MID + 8;
    constexpr int WS1 = CR1 * STA;
    constexpr int WS2 = CR2 * STU;
    constexpr int WSZ = (WS1 > WS2) ? WS1 : WS2;
    __shared__ short As[32 * STA];
    __shared__ short Ws[WSZ];
    __shared__ short U[32 * STU];
    __shared__ float P[32 * 130];

    const int tid  = threadIdx.x;
    const int lane = tid & 63;
    const int wv   = tid >> 6;
    const int col  = lane & 15;
    const int g    = lane >> 4;
    const int m0   = blockIdx.x * 32;
    const int mst  = (wv & 1) * 16;

    for (int i = tid; i < 32 * (K / 8); i += 256) {
        const int r = i / (K / 8), c = (i % (K / 8)) * 8;
        *(bf16x8*)&As[r * STA + c] = *(const bf16x8*)(X + (size_t)(m0 + r) * K + c);
    }

    constexpr int NCH1 = MID / CR1;
    constexpr int NF1  = CR1 / 32;
    const int cb1 = (wv >> 1) * (CR1 / 2);
    #pragma unroll
    for (int ch = 0; ch < NCH1; ++ch) {
        for (int i = tid; i < CR1 * (K / 8); i += 256) {
            const int r = i / (K / 8), c = (i % (K / 8)) * 8;
            *(bf16x8*)&Ws[r * STA + c] =
                *(const bf16x8*)(W1 + (size_t)(ch * CR1 + r) * K + c);
        }
        __syncthreads();
        f32x4 ya[NF1] = {};
        #pragma unroll
        for (int k0 = 0; k0 < K; k0 += 32) {
            bf16x8 a = *(bf16x8*)&As[(mst + col) * STA + k0 + g * 8];
            #pragma unroll
            for (int f = 0; f < NF1; ++f) {
                bf16x8 b = *(bf16x8*)&Ws[(cb1 + f * 16 + col) * STA + k0 + g * 8];
                ya[f] = __builtin_amdgcn_mfma_f32_16x16x32_bf16(a, b, ya[f], 0, 0, 0);
            }
        }
        #pragma unroll
        for (int f = 0; f < NF1; ++f) {
            const int cn = ch * CR1 + cb1 + f * 16 + col;
            const float bb = b1[cn];
            #pragma unroll
            for (int r = 0; r < 4; ++r)
                U[(mst + g * 4 + r) * STU + cn] =
                    f32_to_bf16_rne(fmaxf(ya[f][r] + bb, 0.f));
        }
        __syncthreads();
    }

    constexpr int NCH2 = 128 / CR2;
    constexpr int NF2  = CR2 / 32;
    const int cb2 = (wv >> 1) * (CR2 / 2);
    f32x4 yb[NCH2][NF2] = {};
    #pragma unroll
    for (int ch = 0; ch < NCH2; ++ch) {
        for (int i = tid; i < CR2 * (MID / 8); i += 256) {
            const int r = i / (MID / 8), c = (i % (MID / 8)) * 8;
            *(bf16x8*)&Ws[r * STU + c] =
                *(const bf16x8*)(W2 + (size_t)(ch * CR2 + r) * MID + c);
        }
        __syncthreads();
        #pragma unroll
        for (int k0 = 0; k0 < MID; k0 += 32) {
            bf16x8 a = *(bf16x8*)&U[(mst + col) * STU + k0 + g * 8];
            #pragma unroll
            for (int f = 0; f < NF2; ++f) {
                bf16x8 b = *(bf16x8*)&Ws[(cb2 + f * 16 + col) * STU + k0 + g * 8];
                yb[ch][f] = __builtin_amdgcn_mfma_f32_16x16x32_bf16(a, b, yb[ch][f], 0, 0, 0);
            }
        }
        __syncthreads();
    }

    #pragma unroll
    for (int ch = 0; ch < NCH2; ++ch)
        #pragma unroll
        for (int f = 0; f < NF2; ++f) {
            const int cn = ch * CR2 + cb2 + f * 16 + col;
            const float bb = b2[cn];
            #pragma unroll
            for (int r = 0; r < 4; ++r)
                P[(mst + g * 4 + r) * 130 + cn] = yb[ch][f][r] + bb;
        }
    __syncthreads();

    #pragma unroll
    for (int rr = 0; rr < 8; ++rr) {
        const int row = wv * 8 + rr;
        const size_t t = m0 + row;
        float2 pv = *(float2*)&P[row * 130 + 2 * lane];
        if (DO_LN) {
            float2 hv = ((const float2*)(hf + t * Hh))[lane];
            float a0 = hv.x + pv.x, a1 = hv.y + pv.y;
            float sum = a0 + a1;
            #pragma unroll
            for (int off = 32; off > 0; off >>= 1) sum += __shfl_xor(sum, off);
            const float mean = sum * (1.f / 128.f);
            const float d0 = a0 - mean, d1 = a1 - mean;
            float vs = d0 * d0 + d1 * d1;
            #pragma unroll
            for (int off = 32; off > 0; off >>= 1) vs += __shfl_xor(vs, off);
            const float rstd = rsqrtf(vs * (1.f / 128.f) + 1e-5f);
            float2 gv = ((const float2*)gw)[lane];
            float2 bv = ((const float2*)bw)[lane];
            float2 r = { d0 * rstd * gv.x + bv.x, d1 * rstd * gv.y + bv.y };
            ((float2*)(hf + t * Hh))[lane] = r;
            *(unsigned*)&hb[t * Hh + lane * 2] = pack2_bf16(r.x, r.y);
        } else {
            ((float2*)(hf + t * Hh))[lane] = pv;
            *(unsigned*)&hb[t * Hh + lane * 2] = pack2_bf16(pv.x, pv.y);
        }
    }
}

// ---------------------------------------------------------------------------
// Fused head (R7-verified)
// ---------------------------------------------------------------------------
__global__ __launch_bounds__(256) void head_kernel(
    const short* __restrict__ X,
    const short* __restrict__ W1b, const float* __restrict__ b1,
    const short* __restrict__ DW1b, const float* __restrict__ db1,
    const float* __restrict__ w2, const float* __restrict__ b2,
    const float* __restrict__ dw2, const float* __restrict__ db2,
    float* __restrict__ out)
{
    constexpr int K = 128, ST = K + 8;
    __shared__ short As[32 * ST];
    __shared__ short Ws[64 * ST];
    __shared__ float P[32 * 196];

    const int tid  = threadIdx.x;
    const int lane = tid & 63;
    const int wv   = tid >> 6;
    const int col  = lane & 15;
    const int g    = lane >> 4;
    const int m0   = blockIdx.x * 32;
    const int mst  = (wv & 1) * 16;
    const int cb   = (wv >> 1) * 32;

    for (int i = tid; i < 32 * (K / 8); i += 256) {
        const int r = i / (K / 8), c = (i % (K / 8)) * 8;
        *(bf16x8*)&As[r * ST + c] = *(const bf16x8*)(X + (size_t)(m0 + r) * K + c);
    }

    f32x4 ya[3][2] = {};
    #pragma unroll
    for (int ch = 0; ch < 3; ++ch) {
        for (int i = tid; i < 64 * (K / 8); i += 256) {
            const int r = i / (K / 8), c = (i % (K / 8)) * 8;
            const int rg = ch * 64 + r;
            const short* src = (rg < 128) ? (W1b + (size_t)rg * K)
                                          : (DW1b + (size_t)(rg - 128) * K);
            *(bf16x8*)&Ws[r * ST + c] = *(const bf16x8*)(src + c);
        }
        __syncthreads();
        #pragma unroll
        for (int k0 = 0; k0 < K; k0 += 32) {
            bf16x8 a = *(bf16x8*)&As[(mst + col) * ST + k0 + g * 8];
            #pragma unroll
            for (int f = 0; f < 2; ++f) {
                bf16x8 b = *(bf16x8*)&Ws[(cb + f * 16 + col) * ST + k0 + g * 8];
                ya[ch][f] = __builtin_amdgcn_mfma_f32_16x16x32_bf16(a, b, ya[ch][f], 0, 0, 0);
            }
        }
        __syncthreads();
    }

    #pragma unroll
    for (int ch = 0; ch < 3; ++ch)
        #pragma unroll
        for (int f = 0; f < 2; ++f) {
            const int cn = ch * 64 + cb + f * 16 + col;
            const float bb = (cn < 128) ? b1[cn] : db1[cn - 128];
            #pragma unroll
            for (int r = 0; r < 4; ++r)
                P[(mst + g * 4 + r) * 196 + cn] = fmaxf(ya[ch][f][r] + bb, 0.f);
        }
    __syncthreads();

    const float w20 = w2[2 * lane],       w21 = w2[2 * lane + 1];
    const float w22 = w2[128 + 2 * lane], w23 = w2[129 + 2 * lane];
    const float w24 = w2[256 + 2 * lane], w25 = w2[257 + 2 * lane];
    const float dwl = dw2[lane];
    float qacc = 0.f;
    #pragma unroll
    for (int rr = 0; rr < 8; ++rr) {
        const int row = wv * 8 + rr;
        const size_t t = m0 + row;
        const float x0 = P[row * 196 + 2 * lane];
        const float x1 = P[row * 196 + 2 * lane + 1];
        float s0 = x0 * w20 + x1 * w21;
        float s1 = x0 * w22 + x1 * w23;
        float s2 = x0 * w24 + x1 * w25;
        float d  = P[row * 196 + 128 + lane] * dwl;
        #pragma unroll
        for (int off = 32; off > 0; off >>= 1) {
            s0 += __shfl_xor(s0, off);
            s1 += __shfl_xor(s1, off);
            s2 += __shfl_xor(s2, off);
            d  += __shfl_xor(d,  off);
        }
        if (lane == 0) {
            out[t * 3 + 0] = s0 + b2[0];
            out[t * 3 + 1] = s1 + b2[1];
            out[t * 3 + 2] = s2 + b2[2];
            const float prob = 1.f / (1.f + __expf(-(d + db2[0])));
            out[24576 + t] = prob;
            qacc += prob;
        }
    }
    if (lane == 0)
        atomicAdd(&out[32768 + (m0 >> 11)], qacc * (1.f / (float)Nn));
}

// ---------------------------------------------------------------------------
// MFMA flash attention (R9-verified datapath: no-max softmax + ones-MFMA),
// NEW: head-major qkv layout -> all staging reads fully contiguous.
// Qh/Kh/Vh: [b*NH][N][16], sections of MTOK*128 elems.
// ---------------------------------------------------------------------------
constexpr int KT = 128;
constexpr int KS = 28;
constexpr int VS = 132;

__global__ __launch_bounds__(256) void attn_kernel(
    const short* __restrict__ qkv, short* __restrict__ out)
{
    __shared__ short Ks[KT * KS];
    __shared__ short Vs[DHh * VS];

    const int tid  = threadIdx.x;
    const int lane = tid & 63;
    const int wv   = tid >> 6;
    const int col  = lane & 15;
    const int g    = lane >> 4;
    const int hd   = blockIdx.y;
    const int b    = blockIdx.z;
    const int q0   = blockIdx.x * 64 + wv * 16;

    const size_t bh = (size_t)(b * NHh + hd) * Nn * DHh;
    const short* Qh = qkv + bh;
    const short* Kh = qkv + (size_t)MTOK * 128 + bh;
    const short* Vh = qkv + (size_t)2 * MTOK * 128 + bh;

    bf16x8 qf = {};
    if (g < 2) {
        bf16x8 qraw = *(const bf16x8*)(Qh + (size_t)(q0 + col) * DHh + g * 8);
        const float qs = 0.25f * LOG2E;
        #pragma unroll
        for (int i = 0; i < 8; ++i)
            qf[i] = f32_to_bf16_rne(bf16_to_f32(qraw[i]) * qs);
    }

    f32x4 o    = {0.f, 0.f, 0.f, 0.f};
    f32x4 lacc = {0.f, 0.f, 0.f, 0.f};
    const short one_bf16 = (short)0x3F80;
    const bf16x8 ones = { one_bf16, one_bf16, one_bf16, one_bf16,
                          one_bf16, one_bf16, one_bf16, one_bf16 };

    const int ksr = tid >> 1;              // key 0..127
    const int ksd = (tid & 1) * 8;         // dim half
    const int va  = tid >> 2;              // key pair 2*va
    const int vd  = (tid & 3) * 4;         // dims vd..vd+3

    for (int kt = 0; kt < Nn; kt += KT) {
        __syncthreads();
        {
            *(bf16x8*)&Ks[ksr * KS + ksd] =
                *(const bf16x8*)(Kh + (size_t)(kt + ksr) * DHh + ksd);
            const short* v0 = Vh + (size_t)(kt + 2 * va) * DHh + vd;
            bf16x4 r0 = *(const bf16x4*)v0;
            bf16x4 r1 = *(const bf16x4*)(v0 + DHh);
            unsigned a0 = ((const unsigned*)&r0)[0], a1 = ((const unsigned*)&r0)[1];
            unsigned b0 = ((const unsigned*)&r1)[0], b1 = ((const unsigned*)&r1)[1];
            *(unsigned*)&Vs[(vd + 0) * VS + 2 * va] = __builtin_amdgcn_perm(b0, a0, 0x05040100);
            *(unsigned*)&Vs[(vd + 1) * VS + 2 * va] = __builtin_amdgcn_perm(b0, a0, 0x07060302);
            *(unsigned*)&Vs[(vd + 2) * VS + 2 * va] = __builtin_amdgcn_perm(b1, a1, 0x05040100);
            *(unsigned*)&Vs[(vd + 3) * VS + 2 * va] = __builtin_amdgcn_perm(b1, a1, 0x07060302);
        }
        __syncthreads();

        #pragma unroll
        for (int s = 0; s < 4; ++s) {
            bf16x8 kf0 = {}, kf1 = {};
            if (g < 2) {
                kf0 = *(bf16x8*)&Ks[(s * 32 + col) * KS + g * 8];
                kf1 = *(bf16x8*)&Ks[(s * 32 + 16 + col) * KS + g * 8];
            }
            f32x4 z = {0.f, 0.f, 0.f, 0.f};
            f32x4 sA = __builtin_amdgcn_mfma_f32_16x16x32_bf16(kf0, qf, z, 0, 0, 0);
            f32x4 sB = __builtin_amdgcn_mfma_f32_16x16x32_bf16(kf1, qf, z, 0, 0, 0);

            union { bf16x8 v; unsigned u[4]; } pf;
            pf.u[0] = pack2_bf16(__builtin_amdgcn_exp2f(sA[0]),
                                 __builtin_amdgcn_exp2f(sA[1]));
            pf.u[1] = pack2_bf16(__builtin_amdgcn_exp2f(sA[2]),
                                 __builtin_amdgcn_exp2f(sA[3]));
            pf.u[2] = pack2_bf16(__builtin_amdgcn_exp2f(sB[0]),
                                 __builtin_amdgcn_exp2f(sB[1]));
            pf.u[3] = pack2_bf16(__builtin_amdgcn_exp2f(sB[2]),
                                 __builtin_amdgcn_exp2f(sB[3]));

            bf16x8 vf;
            ((bf16x4*)&vf)[0] = *(bf16x4*)&Vs[col * VS + s * 32 + g * 4];
            ((bf16x4*)&vf)[1] = *(bf16x4*)&Vs[col * VS + s * 32 + 16 + g * 4];

            o    = __builtin_amdgcn_mfma_f32_16x16x32_bf16(pf.v, vf,   o,    0, 0, 0);
            lacc = __builtin_amdgcn_mfma_f32_16x16x32_bf16(pf.v, ones, lacc, 0, 0, 0);
        }
    }

    #pragma unroll
    for (int r = 0; r < 4; ++r) {
        const float inv = __builtin_amdgcn_rcpf(lacc[r]);
        out[(size_t)(b * Nn + q0 + g * 4 + r) * Hh + hd * DHh + col] =
            f32_to_bf16_rne(o[r] * inv);
    }
}

// ---------------------------------------------------------------------------
extern "C" void kernel_launch(void* const* d_in, const int* in_sizes, int n_in,
                              void* d_out, int out_size, void* d_ws, size_t ws_size,
                              hipStream_t stream)
{
    char* W8 = (char*)d_ws;
    float* hf   = (float*)(W8 + 0);            // 4MB  fp32 residual spine
    short* hb   = (short*)(W8 + 4194304);      // 2MB  bf16 mirror
    short* wb   = (short*)(W8 + 6291456);      // 1MB  bf16 weights
    char*  regA = W8 + 7340032;                // 6MB  xb / qkvb (head-major)
    char*  regB = W8 + 13631488;               // 2MB  attno

    short* xb    = (short*)regA;               // [8192,256]
    short* qkvb  = (short*)regA;               // 3 x [32][2048][16]
    short* attno = (short*)regB;               // [8192,128]
    float* out   = (float*)d_out;

    const int wsz[12]  = {32768,16384,49152,16384,32768,32768,49152,16384,32768,32768,16384,8192};
    const int wsrc[12] = {1, 3, 5, 7, 9, 11, 17, 19, 21, 23, 29, 33};
    int woff[13]; woff[0] = 0;
    for (int i = 0; i < 12; ++i) woff[i + 1] = woff[i] + wsz[i];

    CvtJobs jobs;
    int acc = 0;
    for (int i = 0; i < 12; ++i) {
        jobs.src[i] = (const float*)d_in[wsrc[i]];
        jobs.dst[i] = wb + woff[i];
        jobs.off[i] = acc;
        acc += wsz[i] / 4;
    }
    jobs.src[12] = (const float*)d_in[0];
    jobs.dst[12] = xb;
    jobs.off[12] = acc;
    acc += (MTOK * Cc) / 4;
    jobs.off[13] = acc;
    jobs.qzero = out + 32768;

    hipLaunchKernelGGL(cvt_kernel, dim3((acc + 255) / 256), dim3(256), 0, stream, jobs);

    // feature fusion: h = relu(x@fw1^T+b1)@fw2^T+b2  (one fused dispatch)
    hipLaunchKernelGGL((mlp2_kernel<256, 128, 32, 64, false>), dim3(MTOK / 32), dim3(256), 0,
                       stream, xb, wb + woff[0], (const float*)d_in[2],
                       wb + woff[1], (const float*)d_in[4], hf, hb, nullptr, nullptr);

    for (int l = 0; l < 2; ++l) {
        const int ib = 5 + l * 12;
        const int wbase = 2 + l * 4;
        hipLaunchKernelGGL(gemm_qkv_kernel, dim3(384 / 64, MTOK / 64), dim3(256), 0, stream,
                           hb, wb + woff[wbase + 0], (const float*)d_in[ib + 1], qkvb);
        hipLaunchKernelGGL(attn_kernel, dim3(Nn / 64, NHh, Bb), dim3(256), 0, stream,
                           qkvb, attno);
        hipLaunchKernelGGL((gemmln_kernel<128, 64, true>), dim3(MTOK / 32), dim3(256), 0, stream,
                           attno, wb + woff[wbase + 1], (const float*)d_in[ib + 3],
                           hf, hb, (const float*)d_in[ib + 8], (const float*)d_in[ib + 9]);
        // fused FFN: h = LN(h + relu(h@f1^T+b1)@f2^T+b2)
        hipLaunchKernelGGL((mlp2_kernel<128, 256, 64, 32, true>), dim3(MTOK / 32), dim3(256), 0,
                           stream, hb, wb + woff[wbase + 2], (const float*)d_in[ib + 5],
                           wb + woff[wbase + 3], (const float*)d_in[ib + 7],
                           hf, hb, (const float*)d_in[ib + 10], (const float*)d_in[ib + 11]);
    }

    hipLaunchKernelGGL(head_kernel, dim3(MTOK / 32), dim3(256), 0, stream,
                       hb, wb + woff[10], (const float*)d_in[30],
                       wb + woff[11], (const float*)d_in[34],
                       (const float*)d_in[31], (const float*)d_in[32],
                       (const float*)d_in[35], (const float*)d_in[36], out);
}